// Round 1
// baseline (2403.598 us; speedup 1.0000x reference)
//
#include <hip/hip_runtime.h>
#include <hip/hip_fp16.h>
#include <math.h>

// Problem constants
#define NN 4096
#define NP1 4097
#define DD 128
#define ITERS 100

// K is stored as exp(c) * KSCALE in fp16. A uniform scale on the full
// coupling matrix leaves the Sinkhorn transport plan exactly invariant
// (u -> u/KSCALE), so we only need to fold KSCALE back in the epilogue.
#define KSCALE 0.0625f
#define MU_CORE (1.0f/8192.0f)   // exp(norm), m+n = 8192
#define MU_BIN  0.5f             // ns/(ms+ns)
#define INV_SQRT_D 0.08838834764831845f
#define OUT_SCALE 512.0f         // 8192 * KSCALE

// ---------------- GEMM: c[i][j] = sum_d A[d][i]*B[d][j] / sqrt(128) -------
__global__ __launch_bounds__(256) void gemm_kernel(
    const float* __restrict__ A, const float* __restrict__ B,
    float* __restrict__ C) {
  __shared__ float As[16][64];
  __shared__ float Bs[16][64];
  const int tid = threadIdx.x;
  const int tx = tid & 15, ty = tid >> 4;
  const int i0 = blockIdx.y * 64, j0 = blockIdx.x * 64;
  float acc[4][4] = {};
  for (int k0 = 0; k0 < DD; k0 += 16) {
#pragma unroll
    for (int l = 0; l < 4; ++l) {
      int idx = tid + l * 256;
      int r = idx >> 6, cc = idx & 63;
      As[r][cc] = A[(k0 + r) * NN + i0 + cc];
      Bs[r][cc] = B[(k0 + r) * NN + j0 + cc];
    }
    __syncthreads();
#pragma unroll
    for (int kk = 0; kk < 16; ++kk) {
      float a[4], b[4];
#pragma unroll
      for (int r = 0; r < 4; ++r) a[r] = As[kk][ty * 4 + r];
#pragma unroll
      for (int s = 0; s < 4; ++s) b[s] = Bs[kk][tx * 4 + s];
#pragma unroll
      for (int r = 0; r < 4; ++r)
#pragma unroll
        for (int s = 0; s < 4; ++s) acc[r][s] += a[r] * b[s];
    }
    __syncthreads();
  }
  for (int r = 0; r < 4; ++r)
    for (int s = 0; s < 4; ++s)
      C[(long)(i0 + ty * 4 + r) * NN + j0 + tx * 4 + s] = acc[r][s] * INV_SQRT_D;
}

// ------------- build K (fp16) and K^T (fp16) from c (fp32) ----------------
__global__ __launch_bounds__(256) void build_k_kernel(
    const float* __restrict__ C, __half* __restrict__ K,
    __half* __restrict__ KT) {
  __shared__ float tile[64][65];
  const int c0 = blockIdx.x * 64, r0 = blockIdx.y * 64;
  const int tid = threadIdx.x;
#pragma unroll
  for (int l = 0; l < 16; ++l) {
    int idx = tid + l * 256;
    int r = idx >> 6, cc = idx & 63;
    float val = C[(long)(r0 + r) * NN + c0 + cc];
    tile[r][cc] = val;
    K[(long)(r0 + r) * NN + c0 + cc] = __float2half(expf(val) * KSCALE);
  }
  __syncthreads();
#pragma unroll
  for (int l = 0; l < 16; ++l) {
    int idx = tid + l * 256;
    int r = idx >> 6, cc = idx & 63;
    KT[(long)(c0 + r) * NN + r0 + cc] = __float2half(expf(tile[cc][r]) * KSCALE);
  }
}

// ---------------- init v = 1 ----------------------------------------------
__global__ void init_v_kernel(float* __restrict__ v) {
  int i = blockIdx.x * 256 + threadIdx.x;
  if (i <= NN) v[i] = 1.0f;
}

// -------- one Sinkhorn half-step: dst = mu ./ (K_scaled * src + bin) ------
// Works for both u-update (K row-major) and v-update (K^T) by symmetry.
__global__ __launch_bounds__(256) void sinkhorn_kernel(
    const __half* __restrict__ K, const float* __restrict__ src,
    float* __restrict__ dst, const float* __restrict__ alpha_p) {
  const int wave = threadIdx.x >> 6, lane = threadIdx.x & 63;
  const int row = blockIdx.x * 4 + wave;
  const float b = expf(alpha_p[0]) * KSCALE;
  if (row < NN) {
    const __half* Krow = K + (long)row * NN;
    float acc = 0.f;
#pragma unroll
    for (int it = 0; it < 8; ++it) {
      const int j0 = it * 512 + lane * 8;
      const float4 kv4 = *reinterpret_cast<const float4*>(Krow + j0);
      const __half2* kh = reinterpret_cast<const __half2*>(&kv4);
      const float4 v0 = *reinterpret_cast<const float4*>(src + j0);
      const float4 v1 = *reinterpret_cast<const float4*>(src + j0 + 4);
      float2 k0 = __half22float2(kh[0]);
      float2 k1 = __half22float2(kh[1]);
      float2 k2 = __half22float2(kh[2]);
      float2 k3 = __half22float2(kh[3]);
      acc += k0.x * v0.x + k0.y * v0.y + k1.x * v0.z + k1.y * v0.w +
             k2.x * v1.x + k2.y * v1.y + k3.x * v1.z + k3.y * v1.w;
    }
#pragma unroll
    for (int off = 32; off; off >>= 1) acc += __shfl_xor(acc, off);
    if (lane == 0) {
      float denom = acc + b * src[NN];
      dst[row] = MU_CORE / denom;
    }
  } else if (row == NN) {
    // bin row: all entries are b; needs sum of src core + src_bin
    float acc = 0.f;
    for (int j = lane; j < NN; j += 64) acc += src[j];
#pragma unroll
    for (int off = 32; off; off >>= 1) acc += __shfl_xor(acc, off);
    if (lane == 0) dst[NN] = MU_BIN / (b * (acc + src[NN]));
  }
}

// ------- epilogue: out = exp(c)*u*v*8192*KSCALE, fused row max/argmax -----
__global__ __launch_bounds__(256) void final_kernel(
    const float* __restrict__ C, const float* __restrict__ u,
    const float* __restrict__ v, const float* __restrict__ alpha_p,
    float* __restrict__ out, float* __restrict__ rowmax,
    int* __restrict__ rowidx) {
  const int wave = threadIdx.x >> 6, lane = threadIdx.x & 63;
  const int row = blockIdx.x * 4 + wave;
  const float ea = expf(alpha_p[0]);
  if (row < NN) {
    const float ui = u[row] * OUT_SCALE;
    float m = -INFINITY;
    int mi = 0;
    const float* Crow = C + (long)row * NN;
    float* orow = out + (long)row * NP1;
    for (int it = 0; it < 64; ++it) {
      const int j = it * 64 + lane;
      float val = expf(Crow[j]) * ui * v[j];
      orow[j] = val;
      if (val > m) { m = val; mi = j; }  // per-lane first max (ascending j)
    }
#pragma unroll
    for (int off = 1; off < 64; off <<= 1) {
      float om = __shfl_xor(m, off);
      int oi = __shfl_xor(mi, off);
      if (om > m || (om == m && oi < mi)) { m = om; mi = oi; }
    }
    if (lane == 0) {
      orow[NN] = ea * ui * v[NN];  // bin column
      rowmax[row] = m;
      rowidx[row] = mi;
    }
  } else if (row == NN) {
    const float ub = u[NN] * OUT_SCALE;
    float* orow = out + (long)NN * NP1;
    for (int j = lane; j < NN; j += 64) orow[j] = ea * ub * v[j];
    if (lane == 0) orow[NN] = ea * ub * v[NN];  // corner
  }
}

// ---------------- column max/argmax: 2-stage ------------------------------
__global__ __launch_bounds__(256) void colmax_part_kernel(
    const float* __restrict__ out, float* __restrict__ pmax,
    int* __restrict__ pidx) {
  const int col = blockIdx.x * 256 + threadIdx.x;
  const int rg = blockIdx.y;
  float m = -INFINITY;
  int mi = 0;
  const int r0 = rg * 256;
  for (int r = r0; r < r0 + 256; ++r) {
    float val = out[(long)r * NP1 + col];
    if (val > m) { m = val; mi = r; }  // first-max within group
  }
  pmax[rg * NN + col] = m;
  pidx[rg * NN + col] = mi;
}

__global__ __launch_bounds__(256) void colmax_red_kernel(
    const float* __restrict__ pmax, const int* __restrict__ pidx,
    float* __restrict__ colmax, int* __restrict__ colidx) {
  const int col = blockIdx.x * 256 + threadIdx.x;
  float m = -INFINITY;
  int mi = 0;
  for (int rg = 0; rg < 16; ++rg) {
    float val = pmax[rg * NN + col];
    if (val > m) { m = val; mi = pidx[rg * NN + col]; }  // strict >: first max
  }
  colmax[col] = m;
  colidx[col] = mi;
}

// ---------------- mutual matching -----------------------------------------
__global__ void match0_kernel(const float* __restrict__ rowmax,
                              const int* __restrict__ rowidx,
                              const int* __restrict__ colidx,
                              float* __restrict__ out_idx0,
                              float* __restrict__ out_msc0,
                              int* __restrict__ valid0) {
  const int i = blockIdx.x * 256 + threadIdx.x;
  if (i >= NN) return;
  const int i0 = rowidx[i];
  const bool mutual = (colidx[i0] == i);
  const float ms = mutual ? rowmax[i] : 0.f;
  const bool v0 = mutual && (ms > 0.2f);
  out_msc0[i] = ms;
  out_idx0[i] = v0 ? (float)i0 : -1.f;
  valid0[i] = v0 ? 1 : 0;
}

__global__ void match1_kernel(const int* __restrict__ rowidx,
                              const int* __restrict__ colidx,
                              const float* __restrict__ msc0,
                              const int* __restrict__ valid0,
                              float* __restrict__ out_idx1,
                              float* __restrict__ out_msc1) {
  const int j = blockIdx.x * 256 + threadIdx.x;
  if (j >= NN) return;
  const int i1 = colidx[j];
  const bool mutual = (rowidx[i1] == j);
  const float ms = mutual ? msc0[i1] : 0.f;
  const bool v1 = mutual && (valid0[i1] != 0);
  out_msc1[j] = ms;
  out_idx1[j] = v1 ? (float)i1 : -1.f;
}

// ---------------- launch ---------------------------------------------------
extern "C" void kernel_launch(void* const* d_in, const int* in_sizes, int n_in,
                              void* d_out, int out_size, void* d_ws,
                              size_t ws_size, hipStream_t stream) {
  const float* mdesc0 = (const float*)d_in[0];  // (128, 4096)
  const float* mdesc1 = (const float*)d_in[1];  // (128, 4096)
  const float* alpha = (const float*)d_in[2];   // scalar

  char* ws = (char*)d_ws;
  size_t off = 0;
  float* c = (float*)(ws + off); off += (size_t)NN * NN * 4;        // 64 MiB
  __half* K = (__half*)(ws + off); off += (size_t)NN * NN * 2;      // 32 MiB
  __half* KT = (__half*)(ws + off); off += (size_t)NN * NN * 2;     // 32 MiB
  float* u = (float*)(ws + off); off += 16640;
  float* v = (float*)(ws + off); off += 16640;
  float* rowmax = (float*)(ws + off); off += 16384;
  int* rowidx = (int*)(ws + off); off += 16384;
  float* pmax = (float*)(ws + off); off += 16 * NN * 4;
  int* pidx = (int*)(ws + off); off += 16 * NN * 4;
  float* colmax = (float*)(ws + off); off += 16384;
  int* colidx = (int*)(ws + off); off += 16384;
  int* valid0 = (int*)(ws + off); off += 16384;

  float* out = (float*)d_out;
  float* out_idx0 = out + (size_t)NP1 * NP1;
  float* out_idx1 = out_idx0 + NN;
  float* out_msc0 = out_idx1 + NN;
  float* out_msc1 = out_msc0 + NN;

  gemm_kernel<<<dim3(64, 64), 256, 0, stream>>>(mdesc0, mdesc1, c);
  build_k_kernel<<<dim3(64, 64), 256, 0, stream>>>(c, K, KT);
  init_v_kernel<<<17, 256, 0, stream>>>(v);

  for (int t = 0; t < ITERS; ++t) {
    sinkhorn_kernel<<<1025, 256, 0, stream>>>(K, v, u, alpha);
    sinkhorn_kernel<<<1025, 256, 0, stream>>>(KT, u, v, alpha);
  }

  final_kernel<<<1025, 256, 0, stream>>>(c, u, v, alpha, out, rowmax, rowidx);
  colmax_part_kernel<<<dim3(16, 16), 256, 0, stream>>>(out, pmax, pidx);
  colmax_red_kernel<<<16, 256, 0, stream>>>(pmax, pidx, colmax, colidx);
  match0_kernel<<<16, 256, 0, stream>>>(rowmax, rowidx, colidx, out_idx0,
                                        out_msc0, valid0);
  match1_kernel<<<16, 256, 0, stream>>>(rowidx, colidx, out_msc0, valid0,
                                        out_idx1, out_msc1);
}